// Round 1
// baseline (154.168 us; speedup 1.0000x reference)
//
#include <hip/hip_runtime.h>

#define L_LEN   16384
#define P_DIM   512
#define CHUNK   128
#define NCHUNK  128        // L_LEN / CHUNK

#define KDIM    1024       // 2*P (re|im)
#define NDIM    512
#define BM      128
#define BN      128
#define BK      64

typedef __bf16 bf16_t;
typedef __bf16 bf16x8 __attribute__((ext_vector_type(8)));
typedef float  floatx4 __attribute__((ext_vector_type(4)));

// Per-channel discretization constants: a = exp(lambda*step), B = (a-1)/lambda
__device__ __forceinline__ void channel_consts(const float* __restrict__ Lam,
                                               const float* __restrict__ lstep,
                                               int p, float& ar, float& ai,
                                               float& br, float& bi) {
    float lr = -expf(Lam[2 * p + 0]);     // Re(lambda) < 0
    float li = Lam[2 * p + 1];            // Im(lambda)
    float s  = expf(lstep[p]);
    float er = expf(lr * s);
    ar = er * cosf(li * s);
    ai = er * sinf(li * s);
    float dr = ar - 1.0f, di = ai;
    float inv = 1.0f / (lr * lr + li * li);
    br = (dr * lr + di * li) * inv;
    bi = (di * lr - dr * li) * inv;
}

// Phase 1: per (chunk, channel) local scan (zero init), write end state.
__global__ void __launch_bounds__(P_DIM) k_scan_ends(const float* __restrict__ u,
        const float* __restrict__ Lam, const float* __restrict__ lstep,
        float2* __restrict__ endv) {
    int p = threadIdx.x;
    int c = blockIdx.x;
    float ar, ai, br, bi;
    channel_consts(Lam, lstep, p, ar, ai, br, bi);
    float xr = 0.f, xi = 0.f;
    const float* up = u + (size_t)c * CHUNK * P_DIM + p;
    #pragma unroll 8
    for (int k = 0; k < CHUNK; ++k) {
        float uv = up[(size_t)k * P_DIM];
        float nr = ar * xr - ai * xi + br * uv;
        float ni = ar * xi + ai * xr + bi * uv;
        xr = nr; xi = ni;
    }
    endv[c * P_DIM + p] = make_float2(xr, xi);
}

// Phase 2: sequential scan over chunk carries (1 block, 512 threads).
// carry[c] = state entering chunk c. A_chunk = exp(lambda*step*CHUNK) = a^CHUNK.
__global__ void __launch_bounds__(P_DIM) k_carry(const float* __restrict__ Lam,
        const float* __restrict__ lstep, const float2* __restrict__ endv,
        float2* __restrict__ carry) {
    int p = threadIdx.x;
    float lr = -expf(Lam[2 * p + 0]);
    float li = Lam[2 * p + 1];
    float s  = expf(lstep[p]);
    float t  = s * (float)CHUNK;
    float er = expf(lr * t);
    float Ar = er * cosf(li * t);
    float Ai = er * sinf(li * t);
    float xr = 0.f, xi = 0.f;
    #pragma unroll 4
    for (int c = 0; c < NCHUNK; ++c) {
        carry[c * P_DIM + p] = make_float2(xr, xi);
        float2 e = endv[c * P_DIM + p];
        float nr = Ar * xr - Ai * xi + e.x;
        float ni = Ar * xi + Ai * xr + e.y;
        xr = nr; xi = ni;
    }
}

// Phase 3: recompute local scan with carry init; write A = [x_re | x_im] bf16,
// row-major [t][1024].
__global__ void __launch_bounds__(P_DIM) k_materialize(const float* __restrict__ u,
        const float* __restrict__ Lam, const float* __restrict__ lstep,
        const float2* __restrict__ carry, bf16_t* __restrict__ A) {
    int p = threadIdx.x;
    int c = blockIdx.x;
    float ar, ai, br, bi;
    channel_consts(Lam, lstep, p, ar, ai, br, bi);
    float2 x0 = carry[c * P_DIM + p];
    float xr = x0.x, xi = x0.y;
    const float* up = u + (size_t)c * CHUNK * P_DIM + p;
    bf16_t* Ap = A + (size_t)c * CHUNK * KDIM;
    #pragma unroll 4
    for (int k = 0; k < CHUNK; ++k) {
        float uv = up[(size_t)k * P_DIM];
        float nr = ar * xr - ai * xi + br * uv;
        float ni = ar * xi + ai * xr + bi * uv;
        xr = nr; xi = ni;
        Ap[(size_t)k * KDIM + p]         = (bf16_t)xr;
        Ap[(size_t)k * KDIM + P_DIM + p] = (bf16_t)xi;
    }
}

// Pack B operand: Bt[j][k] = (k < 512) ? V_re[j][k] : -V_im[j][k-512], bf16 N x K.
__global__ void __launch_bounds__(256) k_bt(const float* __restrict__ Vre,
        const float* __restrict__ Vim, bf16_t* __restrict__ Bt) {
    int idx = blockIdx.x * 256 + threadIdx.x;   // 0 .. 512*1024-1
    int j = idx >> 10;
    int k = idx & 1023;
    float v = (k < P_DIM) ? Vre[j * P_DIM + k] : -Vim[j * P_DIM + (k - P_DIM)];
    Bt[idx] = (bf16_t)v;
}

// GEMM: out[m][n] = sum_k A[m][k]*Bt[n][k], spike threshold epilogue.
// 128x128 block tile, 4 waves each 64x64 (4x4 of 16x16x32 bf16 MFMA), BK=64.
// LDS layout XOR-swizzled at 16B-chunk granularity: slot (row, sc) holds
// global chunk (row, sc ^ (row&7)) -> frag ds_read_b128 is 2-way only (free).
__global__ void __launch_bounds__(256) k_gemm(const bf16_t* __restrict__ A,
        const bf16_t* __restrict__ Bt, float* __restrict__ out) {
    __shared__ uint4 As4[BM * BK * 2 / 16];   // 16 KB
    __shared__ uint4 Bs4[BN * BK * 2 / 16];   // 16 KB

    const int tid  = threadIdx.x;
    const int lane = tid & 63;
    const int w    = tid >> 6;
    const int m0   = blockIdx.x * BM;
    const int n0   = blockIdx.y * BN;
    const int wm   = (w >> 1) * 64;
    const int wn   = (w & 1) * 64;

    const int fr_m = lane & 15;   // M/N index within 16x16 for A/B operands
    const int fr_g = lane >> 4;   // k-group (quad) 0..3

    floatx4 acc[4][4];
    #pragma unroll
    for (int i = 0; i < 4; ++i)
        #pragma unroll
        for (int j = 0; j < 4; ++j) {
            floatx4 z = {0.f, 0.f, 0.f, 0.f};
            acc[i][j] = z;
        }

    const bf16_t* Asrc = A  + (size_t)m0 * KDIM;
    const bf16_t* Bsrc = Bt + (size_t)n0 * KDIM;

    for (int kt = 0; kt < KDIM; kt += BK) {
        __syncthreads();
        // Stage tiles: 1024 chunks of 16B each, 256 threads x 4.
        #pragma unroll
        for (int i = 0; i < 4; ++i) {
            int q   = i * 256 + tid;       // linear LDS slot
            int row = q >> 3;              // 8 chunks (128B) per row
            int sc  = q & 7;               // swizzled slot col
            int gc  = sc ^ (row & 7);      // global chunk col
            As4[q] = *((const uint4*)(Asrc + (size_t)row * KDIM + kt) + gc);
            Bs4[q] = *((const uint4*)(Bsrc + (size_t)row * KDIM + kt) + gc);
        }
        __syncthreads();
        #pragma unroll
        for (int kk = 0; kk < BK; kk += 32) {
            bf16x8 af[4], bf[4];
            #pragma unroll
            for (int i = 0; i < 4; ++i) {
                int m  = wm + i * 16 + fr_m;
                int cc = (kk >> 3) + fr_g;
                int sc = cc ^ (m & 7);
                af[i] = *(const bf16x8*)((const bf16_t*)As4 + m * BK + sc * 8);
            }
            #pragma unroll
            for (int j = 0; j < 4; ++j) {
                int n  = wn + j * 16 + fr_m;
                int cc = (kk >> 3) + fr_g;
                int sc = cc ^ (n & 7);
                bf[j] = *(const bf16x8*)((const bf16_t*)Bs4 + n * BK + sc * 8);
            }
            #pragma unroll
            for (int i = 0; i < 4; ++i)
                #pragma unroll
                for (int j = 0; j < 4; ++j)
                    acc[i][j] = __builtin_amdgcn_mfma_f32_16x16x32_bf16(
                        af[i], bf[j], acc[i][j], 0, 0, 0);
        }
    }

    // Epilogue: C/D layout col=lane&15, row=(lane>>4)*4+reg (m89-verified).
    #pragma unroll
    for (int i = 0; i < 4; ++i)
        #pragma unroll
        for (int j = 0; j < 4; ++j)
            #pragma unroll
            for (int r = 0; r < 4; ++r) {
                int rr = wm + i * 16 + fr_g * 4 + r;
                int cl = wn + j * 16 + fr_m;
                float v = acc[i][j][r];
                out[(size_t)(m0 + rr) * NDIM + (n0 + cl)] = (v > 1.0f) ? 1.0f : 0.0f;
            }
}

extern "C" void kernel_launch(void* const* d_in, const int* in_sizes, int n_in,
                              void* d_out, int out_size, void* d_ws, size_t ws_size,
                              hipStream_t stream) {
    (void)in_sizes; (void)n_in; (void)out_size; (void)ws_size;
    const float* u     = (const float*)d_in[0];
    const float* Lam   = (const float*)d_in[1];
    const float* lstep = (const float*)d_in[2];
    const float* Vre   = (const float*)d_in[3];
    const float* Vim   = (const float*)d_in[4];
    float* out = (float*)d_out;

    char* ws = (char*)d_ws;
    const size_t endv_bytes  = (size_t)NCHUNK * P_DIM * sizeof(float2);   // 512 KB
    const size_t carry_bytes = endv_bytes;                                // 512 KB
    const size_t bt_bytes    = (size_t)NDIM * KDIM * sizeof(bf16_t);      // 1 MB
    float2* endv  = (float2*)(ws);
    float2* carry = (float2*)(ws + endv_bytes);
    bf16_t* Bt    = (bf16_t*)(ws + endv_bytes + carry_bytes);
    bf16_t* A     = (bf16_t*)(ws + endv_bytes + carry_bytes + bt_bytes);  // 32 MB

    hipLaunchKernelGGL(k_scan_ends, dim3(NCHUNK), dim3(P_DIM), 0, stream,
                       u, Lam, lstep, endv);
    hipLaunchKernelGGL(k_bt, dim3(NDIM * KDIM / 256), dim3(256), 0, stream,
                       Vre, Vim, Bt);
    hipLaunchKernelGGL(k_carry, dim3(1), dim3(P_DIM), 0, stream,
                       Lam, lstep, endv, carry);
    hipLaunchKernelGGL(k_materialize, dim3(NCHUNK), dim3(P_DIM), 0, stream,
                       u, Lam, lstep, carry, A);
    hipLaunchKernelGGL(k_gemm, dim3(L_LEN / BM, NDIM / BN), dim3(256), 0, stream,
                       A, Bt, out);
}